// Round 3
// baseline (5340.009 us; speedup 1.0000x reference)
//
#include <hip/hip_runtime.h>

#define DD 64

// 16 lanes per edge, float4 per lane.
// sum[dst*64 + l*4 .. +3] += emb[src][l*4..] * weight[type][l*4..]  (f32 atomics)
__global__ void scatter_kernel(const float4* __restrict__ emb4,
                               const float4* __restrict__ weight4,
                               const int* __restrict__ dst_idx,
                               const int* __restrict__ src_idx,
                               const int* __restrict__ etype,   // nullptr -> type 0
                               float* __restrict__ sum,
                               float* __restrict__ cnt,
                               int n_edges) {
    int e = blockIdx.x * (blockDim.x >> 4) + (threadIdx.x >> 4);
    int l = threadIdx.x & 15;
    if (e >= n_edges) return;
    int dst = dst_idx[e];
    int src = src_idx[e];
    int t = etype ? etype[e] : 0;
    float4 v = emb4[(size_t)src * 16 + l];
    float4 w = weight4[t * 16 + l];
    float* s = &sum[(size_t)dst * DD + l * 4];
    atomicAdd(s + 0, v.x * w.x);
    atomicAdd(s + 1, v.y * w.y);
    atomicAdd(s + 2, v.z * w.z);
    atomicAdd(s + 3, v.w * w.w);
    if (l == 0) atomicAdd(&cnt[dst], 1.0f);
}

// out = sig(a@gA.T + b@gB.T) * a + (1-sig) * b; a=asum/max(acnt,1), b=bsum/max(bcnt,1)
// Grid-stride over rows; gates staged transposed in LDS once per block.
// LDS padded to 65: staging write GA[i&63][i>>6] -> bank (k*65+d)%32 = (k+d)%32,
// conflict-free; read GA[k][lane] -> 2 lanes/bank, free.
__global__ void gate_fuse_kernel(const float* __restrict__ asum, const float* __restrict__ acnt,
                                 const float* __restrict__ bsum, const float* __restrict__ bcnt,
                                 const float* __restrict__ gA,
                                 const float* __restrict__ gB,
                                 float* __restrict__ out,
                                 int n_rows) {
    __shared__ float GA[DD][DD + 1];   // GA[k][d] = gA[d][k]
    __shared__ float GB[DD][DD + 1];
    for (int i = threadIdx.x; i < DD * DD; i += blockDim.x) {
        int d = i >> 6, k = i & 63;
        GA[k][d] = gA[i];
        GB[k][d] = gB[i];
    }
    __syncthreads();
    int lane = threadIdx.x & 63;
    int waves_per_blk = blockDim.x >> 6;
    int row0 = blockIdx.x * waves_per_blk + (threadIdx.x >> 6);
    int stride = gridDim.x * waves_per_blk;
    for (int row = row0; row < n_rows; row += stride) {
        float ca = acnt[row]; ca = ca < 1.f ? 1.f : ca;
        float cb = bcnt[row]; cb = cb < 1.f ? 1.f : cb;
        float a = asum[(size_t)row * DD + lane] / ca;
        float b = bsum[(size_t)row * DD + lane] / cb;
        float z = 0.f;
        #pragma unroll
        for (int k = 0; k < DD; ++k) {
            float ak = __shfl(a, k, 64);
            float bk = __shfl(b, k, 64);
            z += ak * GA[k][lane] + bk * GB[k][lane];
        }
        float g = 1.f / (1.f + expf(-z));
        out[(size_t)row * DD + lane] = g * a + (1.f - g) * b;
    }
}

// out[row] = sum[row]/max(cnt[row],1) for row in [row_start, row_end); float4 lanes
__global__ void mean_tail_kernel(const float4* __restrict__ sum4, const float* __restrict__ cnt,
                                 float4* __restrict__ out4,
                                 int row_start, int row_end) {
    int idx = blockIdx.x * blockDim.x + threadIdx.x;
    int row = row_start + (idx >> 4);
    if (row >= row_end) return;
    int l = idx & 15;
    float c = cnt[row]; c = c < 1.f ? 1.f : c;
    float inv = 1.f / c;
    float4 v = sum4[(size_t)row * 16 + l];
    v.x *= inv; v.y *= inv; v.z *= inv; v.w *= inv;
    out4[(size_t)row * 16 + l] = v;
}

extern "C" void kernel_launch(void* const* d_in, const int* in_sizes, int n_in,
                              void* d_out, int out_size, void* d_ws, size_t ws_size,
                              hipStream_t stream) {
    const float* entity_emb = (const float*)d_in[0];
    const float* user_emb   = (const float*)d_in[1];
    const float* weight     = (const float*)d_in[2];
    const float* g1         = (const float*)d_in[3];
    const float* g2         = (const float*)d_in[4];
    const float* g3         = (const float*)d_in[5];
    const int* edge_index  = (const int*)d_in[6];   // (2, E): row0=head(dst), row1=tail(src)
    const int* edge_type   = (const int*)d_in[7];
    const int* uedge_index = (const int*)d_in[8];   // (2, UE)
    const int* uedge_type  = (const int*)d_in[9];
    const int* mat_row     = (const int*)d_in[10];  // users
    const int* mat_col     = (const int*)d_in[11];  // items

    const int n_entities   = in_sizes[0] / DD;  // 180000
    const int n_user_nodes = in_sizes[1] / DD;  // 150000
    const int n_edges      = in_sizes[7];       // 1500000
    const int n_uedges     = in_sizes[9];       // 1000000
    const int n_mat        = in_sizes[10];      // 1500000
    const int n_items      = 50000;
    const int n_users      = 100000;

    // f32 workspace layout
    float* ws = (float*)d_ws;
    size_t off = 0;
    float* esum  = ws + off; off += (size_t)n_entities * DD;
    float* asum  = ws + off; off += (size_t)n_user_nodes * DD;
    float* iusum = ws + off; off += (size_t)n_items * DD;
    float* uisum = ws + off; off += (size_t)n_users * DD;
    float* ecnt  = ws + off; off += n_entities;
    float* acnt  = ws + off; off += n_user_nodes;
    float* iucnt = ws + off; off += n_items;
    float* uicnt = ws + off; off += n_users;
    hipMemsetAsync(d_ws, 0, off * sizeof(float), stream);

    dim3 blk(256);  // 16 edges/block for scatter

    // entity_agg = scatter_mean(entity_emb[tail]*weight[edge_type], head)
    scatter_kernel<<<(n_edges + 15) / 16, blk, 0, stream>>>(
        (const float4*)entity_emb, (const float4*)weight,
        edge_index, edge_index + n_edges, edge_type, esum, ecnt, n_edges);
    // attribute_agg = scatter_mean(user_emb[utail]*weight[user_edge_type], uhead)
    scatter_kernel<<<(n_uedges + 15) / 16, blk, 0, stream>>>(
        (const float4*)user_emb, (const float4*)weight,
        uedge_index, uedge_index + n_uedges, uedge_type, asum, acnt, n_uedges);
    // i_u_agg = scatter_mean(user_emb[mat_row]*weight[0], mat_col, N_ITEMS)
    scatter_kernel<<<(n_mat + 15) / 16, blk, 0, stream>>>(
        (const float4*)user_emb, (const float4*)weight,
        mat_col, mat_row, nullptr, iusum, iucnt, n_mat);
    // u_i_agg = scatter_mean(entity_emb[mat_col]*weight[0], mat_row, N_USERS)
    scatter_kernel<<<(n_mat + 15) / 16, blk, 0, stream>>>(
        (const float4*)entity_emb, (const float4*)weight,
        mat_row, mat_col, nullptr, uisum, uicnt, n_mat);

    float* out      = (float*)d_out;
    float* user_out = out + (size_t)n_entities * DD;

    // items: gi = sig(item_kg@g1.T + i_u@g2.T); out = gi*item_kg + (1-gi)*i_u
    gate_fuse_kernel<<<1024, blk, 0, stream>>>(
        esum, ecnt, iusum, iucnt, g1, g2, out, n_items);
    // entity tail rows [n_items, n_entities)
    {
        long long threads = (long long)(n_entities - n_items) * 16;
        mean_tail_kernel<<<(unsigned)((threads + 255) / 256), blk, 0, stream>>>(
            (const float4*)esum, ecnt, (float4*)out, n_items, n_entities);
    }
    // users: hi = sig(u_i@g2.T + ukg@g3.T); out = hi*ukg + (1-hi)*u_i
    //   a = ukg (asum/acnt) paired with g3, b = u_i (uisum/uicnt) paired with g2
    gate_fuse_kernel<<<2048, blk, 0, stream>>>(
        asum, acnt, uisum, uicnt, g3, g2, user_out, n_users);
    // user tail rows [n_users, n_user_nodes)
    {
        long long threads = (long long)(n_user_nodes - n_users) * 16;
        mean_tail_kernel<<<(unsigned)((threads + 255) / 256), blk, 0, stream>>>(
            (const float4*)asum, acnt, (float4*)user_out, n_users, n_user_nodes);
    }
}

// Round 4
// 1660.753 us; speedup vs baseline: 3.2154x; 3.2154x over previous
//
#include <hip/hip_runtime.h>

#define DD 64

// ---------- CSR build ----------

__global__ void hist_kernel(const int* __restrict__ dst, int* __restrict__ cnt, int n) {
    int i = blockIdx.x * blockDim.x + threadIdx.x;
    if (i < n) atomicAdd(&cnt[dst[i]], 1);
}

// Exclusive scan, 1024 elems per block (256 thr x 4). Writes per-block total to bsums.
__global__ void scan_blocks(const int* __restrict__ in, int* __restrict__ out,
                            int* __restrict__ bsums, int n) {
    __shared__ int ts[256];
    int base = blockIdx.x * 1024;
    int t = threadIdx.x;
    int v[4];
    int loc = 0;
#pragma unroll
    for (int k = 0; k < 4; ++k) {
        int i = base + t * 4 + k;
        v[k] = (i < n) ? in[i] : 0;
        loc += v[k];
    }
    ts[t] = loc;
    __syncthreads();
    for (int off = 1; off < 256; off <<= 1) {
        int x = (t >= off) ? ts[t - off] : 0;
        __syncthreads();
        ts[t] += x;
        __syncthreads();
    }
    if (t == 255) bsums[blockIdx.x] = ts[255];
    int run = (t == 0) ? 0 : ts[t - 1];
#pragma unroll
    for (int k = 0; k < 4; ++k) {
        int i = base + t * 4 + k;
        if (i < n) out[i] = run;
        run += v[k];
    }
}

// Exclusive scan of block sums (nb <= ~200), single thread — trivial work.
__global__ void scan_sums(int* __restrict__ bsums, int nb) {
    if (threadIdx.x == 0 && blockIdx.x == 0) {
        int acc = 0;
        for (int i = 0; i < nb; ++i) { int v = bsums[i]; bsums[i] = acc; acc += v; }
    }
}

__global__ void add_offsets(int* __restrict__ out, const int* __restrict__ bsums, int n) {
    int i = blockIdx.x * blockDim.x + threadIdx.x;
    if (i < n) out[i] += bsums[i >> 10];
}

// pay[pos] = src | (type<<20). Consumes rowptr as cursor: after this kernel
// rowptr[d] = end offset of row d (start = rowptr[d-1], or 0 for d==0).
__global__ void fill_kernel(const int* __restrict__ dst, const int* __restrict__ src,
                            const int* __restrict__ et,  // nullptr -> type 0
                            int* __restrict__ rowptr, int* __restrict__ pay, int n) {
    int i = blockIdx.x * blockDim.x + threadIdx.x;
    if (i < n) {
        int d = dst[i];
        int pos = atomicAdd(&rowptr[d], 1);
        int t = et ? et[i] : 0;
        pay[pos] = src[i] | (t << 20);
    }
}

// ---------- gather-reduce (the former scatter, atomic-free) ----------
// One wave per destination row; lane = feature dim. mean = sum(emb[src]*w[t]) / max(deg,1).
// Rows < split -> out_head[row]; rows >= split -> out_tail (full-size array, same row id).
__global__ void gather_kernel(const float* __restrict__ emb, const float* __restrict__ weight,
                              const int* __restrict__ rowptr, const int* __restrict__ pay,
                              float* __restrict__ out_head, float* __restrict__ out_tail,
                              int split, int n_dst) {
    int w = blockIdx.x * (blockDim.x >> 6) + (threadIdx.x >> 6);
    int lane = threadIdx.x & 63;
    if (w >= n_dst) return;
    int start = (w == 0) ? 0 : rowptr[w - 1];
    int end = rowptr[w];
    float acc = 0.f;
    for (int j = start; j < end; ++j) {
        int p = pay[j];
        int src = p & 0xFFFFF;
        int t = p >> 20;
        acc += emb[(size_t)src * DD + lane] * weight[t * DD + lane];
    }
    int deg = end - start;
    float mean = acc / (float)(deg > 0 ? deg : 1);
    if (w < split) out_head[(size_t)w * DD + lane] = mean;
    else           out_tail[(size_t)w * DD + lane] = mean;
}

// ---------- gated fusion ----------
// out = sig(a@gA.T + b@gB.T) * a + (1-sig) * b. Grid-stride; gates transposed in LDS,
// padded to 65 so staging writes are conflict-free and reads are 2-way (free).
__global__ void gate_fuse_kernel(const float* __restrict__ a_, const float* __restrict__ b_,
                                 const float* __restrict__ gA, const float* __restrict__ gB,
                                 float* __restrict__ out, int n_rows) {
    __shared__ float GA[DD][DD + 1];   // GA[k][d] = gA[d][k]
    __shared__ float GB[DD][DD + 1];
    for (int i = threadIdx.x; i < DD * DD; i += blockDim.x) {
        int d = i >> 6, k = i & 63;
        GA[k][d] = gA[i];
        GB[k][d] = gB[i];
    }
    __syncthreads();
    int lane = threadIdx.x & 63;
    int waves_per_blk = blockDim.x >> 6;
    int row0 = blockIdx.x * waves_per_blk + (threadIdx.x >> 6);
    int stride = gridDim.x * waves_per_blk;
    for (int row = row0; row < n_rows; row += stride) {
        float a = a_[(size_t)row * DD + lane];
        float b = b_[(size_t)row * DD + lane];
        float z = 0.f;
#pragma unroll
        for (int k = 0; k < DD; ++k) {
            float ak = __shfl(a, k, 64);
            float bk = __shfl(b, k, 64);
            z += ak * GA[k][lane] + bk * GB[k][lane];
        }
        float g = 1.f / (1.f + expf(-z));
        out[(size_t)row * DD + lane] = g * a + (1.f - g) * b;
    }
}

// ---------- driver ----------

static void run_agg(const int* dst, const int* src, const int* et, int n_edges, int n_dst,
                    const float* emb, const float* weight,
                    float* out_head, float* out_tail, int split,
                    int* counts, int* rowptr, int* bsums, int* pay, hipStream_t stream) {
    hipMemsetAsync(counts, 0, (size_t)n_dst * sizeof(int), stream);
    unsigned gE = (n_edges + 255) / 256;
    hist_kernel<<<gE, 256, 0, stream>>>(dst, counts, n_edges);
    int nb = (n_dst + 1023) / 1024;
    scan_blocks<<<nb, 256, 0, stream>>>(counts, rowptr, bsums, n_dst);
    scan_sums<<<1, 64, 0, stream>>>(bsums, nb);
    add_offsets<<<(n_dst + 255) / 256, 256, 0, stream>>>(rowptr, bsums, n_dst);
    fill_kernel<<<gE, 256, 0, stream>>>(dst, src, et, rowptr, pay, n_edges);
    gather_kernel<<<(n_dst + 3) / 4, 256, 0, stream>>>(emb, weight, rowptr, pay,
                                                       out_head, out_tail, split, n_dst);
}

extern "C" void kernel_launch(void* const* d_in, const int* in_sizes, int n_in,
                              void* d_out, int out_size, void* d_ws, size_t ws_size,
                              hipStream_t stream) {
    const float* entity_emb = (const float*)d_in[0];
    const float* user_emb   = (const float*)d_in[1];
    const float* weight     = (const float*)d_in[2];
    const float* g1         = (const float*)d_in[3];
    const float* g2         = (const float*)d_in[4];
    const float* g3         = (const float*)d_in[5];
    const int* edge_index  = (const int*)d_in[6];   // (2,E): row0=head(dst), row1=tail(src)
    const int* edge_type   = (const int*)d_in[7];
    const int* uedge_index = (const int*)d_in[8];   // (2,UE)
    const int* uedge_type  = (const int*)d_in[9];
    const int* mat_row     = (const int*)d_in[10];  // user ids
    const int* mat_col     = (const int*)d_in[11];  // item ids

    const int n_entities   = in_sizes[0] / DD;  // 180000
    const int n_user_nodes = in_sizes[1] / DD;  // 150000
    const int n_edges      = in_sizes[7];       // 1500000
    const int n_uedges     = in_sizes[9];       // 1000000
    const int n_mat        = in_sizes[10];      // 1500000
    const int n_items      = 50000;
    const int n_users      = 100000;

    float* out      = (float*)d_out;
    float* user_out = out + (size_t)n_entities * DD;

    // workspace layout (~84 MB)
    float* ws = (float*)d_ws;
    size_t off = 0;
    float* kg_item = ws + off; off += (size_t)n_items * DD;   // entity_agg[:n_items]
    float* ukg     = ws + off; off += (size_t)n_users * DD;   // attribute_agg[:n_users]
    float* iu      = ws + off; off += (size_t)n_items * DD;   // i_u_agg
    float* ui      = ws + off; off += (size_t)n_users * DD;   // u_i_agg
    int* ibase = (int*)(ws + off);
    int* counts = ibase;             // 180000
    int* rowptr = ibase + 180000;    // 180000
    int* bsums  = ibase + 360000;    // 256
    int* pay    = ibase + 360256;    // n_edges max (1.5M)

    // entity_agg = scatter_mean(entity_emb[tail]*w[type], head, N_ENTITIES)
    //   head rows [0,n_items) -> kg_item, tail rows -> out directly
    run_agg(edge_index, edge_index + n_edges, edge_type, n_edges, n_entities,
            entity_emb, weight, kg_item, out, n_items,
            counts, rowptr, bsums, pay, stream);
    // attribute_agg = scatter_mean(user_emb[utail]*w[utype], uhead, N_USER_NODES)
    run_agg(uedge_index, uedge_index + n_uedges, uedge_type, n_uedges, n_user_nodes,
            user_emb, weight, ukg, user_out, n_users,
            counts, rowptr, bsums, pay, stream);
    // i_u_agg = scatter_mean(user_emb[mat_row]*w[0], mat_col, N_ITEMS)
    run_agg(mat_col, mat_row, nullptr, n_mat, n_items,
            user_emb, weight, iu, iu, n_items,
            counts, rowptr, bsums, pay, stream);
    // u_i_agg = scatter_mean(entity_emb[mat_col]*w[0], mat_row, N_USERS)
    run_agg(mat_row, mat_col, nullptr, n_mat, n_users,
            entity_emb, weight, ui, ui, n_users,
            counts, rowptr, bsums, pay, stream);

    // items: gi = sig(kg@g1.T + iu@g2.T); out = gi*kg + (1-gi)*iu
    gate_fuse_kernel<<<1024, 256, 0, stream>>>(kg_item, iu, g1, g2, out, n_items);
    // users: hi = sig(ui@g2.T + ukg@g3.T); out = hi*ukg + (1-hi)*ui
    gate_fuse_kernel<<<2048, 256, 0, stream>>>(ukg, ui, g3, g2, user_out, n_users);
}

// Round 5
// 1255.939 us; speedup vs baseline: 4.2518x; 1.3223x over previous
//
#include <hip/hip_runtime.h>

#define DD 64

// ---------- batched CSR build over concatenated destination row space ----------
// Segments (global row offsets): A entity[0,180k) B user[180k,330k) C item[330k,380k) D user[380k,480k)

__global__ void hist_all(const int* __restrict__ dA, const int* __restrict__ dB,
                         const int* __restrict__ dC, const int* __restrict__ dD,
                         int nA, int nB, int nC, int nD,
                         int offA, int offB, int offC, int offD,
                         int* __restrict__ counts) {
    int i = blockIdx.x * blockDim.x + threadIdx.x;
    int d, off;
    if (i < nA) { d = dA[i]; off = offA; }
    else if ((i -= nA) < nB) { d = dB[i]; off = offB; }
    else if ((i -= nB) < nC) { d = dC[i]; off = offC; }
    else if ((i -= nC) < nD) { d = dD[i]; off = offD; }
    else return;
    atomicAdd(&counts[off + d], 1);
}

// Exclusive scan, 1024 elems per block (256 thr x 4). Per-block totals -> bsums.
__global__ void scan_blocks(const int* __restrict__ in, int* __restrict__ out,
                            int* __restrict__ bsums, int n) {
    __shared__ int ts[256];
    int base = blockIdx.x * 1024;
    int t = threadIdx.x;
    int v[4];
    int loc = 0;
#pragma unroll
    for (int k = 0; k < 4; ++k) {
        int i = base + t * 4 + k;
        v[k] = (i < n) ? in[i] : 0;
        loc += v[k];
    }
    ts[t] = loc;
    __syncthreads();
    for (int off = 1; off < 256; off <<= 1) {
        int x = (t >= off) ? ts[t - off] : 0;
        __syncthreads();
        ts[t] += x;
        __syncthreads();
    }
    if (t == 255) bsums[blockIdx.x] = ts[255];
    int run = (t == 0) ? 0 : ts[t - 1];
#pragma unroll
    for (int k = 0; k < 4; ++k) {
        int i = base + t * 4 + k;
        if (i < n) out[i] = run;
        run += v[k];
    }
}

// Exclusive scan of block sums, one 512-thread block (nb <= 512).
__global__ void scan_sums(int* __restrict__ bsums, int nb) {
    __shared__ int ts[512];
    int t = threadIdx.x;
    int v = (t < nb) ? bsums[t] : 0;
    ts[t] = v;
    __syncthreads();
    for (int off = 1; off < 512; off <<= 1) {
        int x = (t >= off) ? ts[t - off] : 0;
        __syncthreads();
        ts[t] += x;
        __syncthreads();
    }
    if (t < nb) bsums[t] = ts[t] - v;   // exclusive
}

__global__ void add_offsets(int* __restrict__ out, const int* __restrict__ bsums, int n) {
    int i = blockIdx.x * blockDim.x + threadIdx.x;
    if (i < n) out[i] += bsums[i >> 10];
}

// pay[pos] = src | (type<<20); consumes rowptr as cursor (after: rowptr[w] = row end).
__global__ void fill_all(const int* __restrict__ dA, const int* __restrict__ sA, const int* __restrict__ tA,
                         const int* __restrict__ dB, const int* __restrict__ sB, const int* __restrict__ tB,
                         const int* __restrict__ dC, const int* __restrict__ sC,
                         const int* __restrict__ dD, const int* __restrict__ sD,
                         int nA, int nB, int nC, int nD,
                         int offA, int offB, int offC, int offD,
                         int* __restrict__ rowptr, int* __restrict__ pay) {
    int i = blockIdx.x * blockDim.x + threadIdx.x;
    int d, s, t, off;
    if (i < nA) { d = dA[i]; s = sA[i]; t = tA[i]; off = offA; }
    else if ((i -= nA) < nB) { d = dB[i]; s = sB[i]; t = tB[i]; off = offB; }
    else if ((i -= nB) < nC) { d = dC[i]; s = sC[i]; t = 0; off = offC; }
    else if ((i -= nC) < nD) { d = dD[i]; s = sD[i]; t = 0; off = offD; }
    else return;
    int pos = atomicAdd(&rowptr[off + d], 1);
    pay[pos] = s | (t << 20);
}

// ---------- combined gather-reduce ----------
// One wave per global destination row. Payloads fetched 64-at-a-time with one
// coalesced per-lane load, broadcast via shfl; edge loop unrolled x4 for MLP.
__global__ void gather_all(const float* __restrict__ entity_emb,
                           const float* __restrict__ user_emb,
                           const float* __restrict__ weight,
                           const int* __restrict__ rowptr, const int* __restrict__ pay,
                           float* __restrict__ kg_item, float* __restrict__ ent_out,
                           float* __restrict__ ukg, float* __restrict__ usr_out,
                           float* __restrict__ iu, float* __restrict__ ui,
                           int offB, int offC, int offD, int n_rows,
                           int n_items, int n_users) {
    int w = blockIdx.x * (blockDim.x >> 6) + (threadIdx.x >> 6);
    int lane = threadIdx.x & 63;
    if (w >= n_rows) return;

    const float* emb;
    float* dst;
    int r;
    if (w < offB)      { r = w;        emb = entity_emb; dst = (r < n_items) ? kg_item + ((size_t)r * DD)
                                                                             : ent_out + ((size_t)r * DD); }
    else if (w < offC) { r = w - offB; emb = user_emb;   dst = (r < n_users) ? ukg + ((size_t)r * DD)
                                                                             : usr_out + ((size_t)r * DD); }
    else if (w < offD) { r = w - offC; emb = user_emb;   dst = iu + ((size_t)r * DD); }
    else               { r = w - offD; emb = entity_emb; dst = ui + ((size_t)r * DD); }

    int start = (w == 0) ? 0 : rowptr[w - 1];
    int end = rowptr[w];
    float acc = 0.f;
    for (int base = start; base < end; base += 64) {
        int m = end - base; if (m > 64) m = 64;
        int p = (lane < m) ? pay[base + lane] : 0;
        int j = 0;
        for (; j + 4 <= m; j += 4) {
            int p0 = __shfl(p, j, 64), p1 = __shfl(p, j + 1, 64);
            int p2 = __shfl(p, j + 2, 64), p3 = __shfl(p, j + 3, 64);
            float e0 = emb[((p0 & 0xFFFFF) << 6) + lane];
            float w0 = weight[((p0 >> 20) << 6) + lane];
            float e1 = emb[((p1 & 0xFFFFF) << 6) + lane];
            float w1 = weight[((p1 >> 20) << 6) + lane];
            float e2 = emb[((p2 & 0xFFFFF) << 6) + lane];
            float w2 = weight[((p2 >> 20) << 6) + lane];
            float e3 = emb[((p3 & 0xFFFFF) << 6) + lane];
            float w3 = weight[((p3 >> 20) << 6) + lane];
            acc += e0 * w0; acc += e1 * w1; acc += e2 * w2; acc += e3 * w3;
        }
        for (; j < m; ++j) {
            int pj = __shfl(p, j, 64);
            acc += emb[((pj & 0xFFFFF) << 6) + lane] * weight[((pj >> 20) << 6) + lane];
        }
    }
    int deg = end - start;
    dst[lane] = acc / (float)(deg > 0 ? deg : 1);
}

// ---------- gated fusion ----------
__global__ void gate_fuse_kernel(const float* __restrict__ a_, const float* __restrict__ b_,
                                 const float* __restrict__ gA, const float* __restrict__ gB,
                                 float* __restrict__ out, int n_rows) {
    __shared__ float GA[DD][DD + 1];   // GA[k][d] = gA[d][k]
    __shared__ float GB[DD][DD + 1];
    for (int i = threadIdx.x; i < DD * DD; i += blockDim.x) {
        int d = i >> 6, k = i & 63;
        GA[k][d] = gA[i];
        GB[k][d] = gB[i];
    }
    __syncthreads();
    int lane = threadIdx.x & 63;
    int waves_per_blk = blockDim.x >> 6;
    int row0 = blockIdx.x * waves_per_blk + (threadIdx.x >> 6);
    int stride = gridDim.x * waves_per_blk;
    for (int row = row0; row < n_rows; row += stride) {
        float a = a_[(size_t)row * DD + lane];
        float b = b_[(size_t)row * DD + lane];
        float z = 0.f;
#pragma unroll
        for (int k = 0; k < DD; ++k) {
            float ak = __shfl(a, k, 64);
            float bk = __shfl(b, k, 64);
            z += ak * GA[k][lane] + bk * GB[k][lane];
        }
        float g = 1.f / (1.f + expf(-z));
        out[(size_t)row * DD + lane] = g * a + (1.f - g) * b;
    }
}

extern "C" void kernel_launch(void* const* d_in, const int* in_sizes, int n_in,
                              void* d_out, int out_size, void* d_ws, size_t ws_size,
                              hipStream_t stream) {
    const float* entity_emb = (const float*)d_in[0];
    const float* user_emb   = (const float*)d_in[1];
    const float* weight     = (const float*)d_in[2];
    const float* g1         = (const float*)d_in[3];
    const float* g2         = (const float*)d_in[4];
    const float* g3         = (const float*)d_in[5];
    const int* edge_index  = (const int*)d_in[6];   // (2,E): row0=head(dst), row1=tail(src)
    const int* edge_type   = (const int*)d_in[7];
    const int* uedge_index = (const int*)d_in[8];   // (2,UE)
    const int* uedge_type  = (const int*)d_in[9];
    const int* mat_row     = (const int*)d_in[10];  // user ids
    const int* mat_col     = (const int*)d_in[11];  // item ids

    const int n_entities   = in_sizes[0] / DD;  // 180000
    const int n_user_nodes = in_sizes[1] / DD;  // 150000
    const int nA           = in_sizes[7];       // 1500000 entity edges
    const int nB           = in_sizes[9];       // 1000000 user edges
    const int nM           = in_sizes[10];      // 1500000 interaction edges
    const int n_items      = 50000;
    const int n_users      = 100000;

    const int offA = 0;
    const int offB = n_entities;                // 180000
    const int offC = offB + n_user_nodes;       // 330000
    const int offD = offC + n_items;            // 380000
    const int R    = offD + n_users;            // 480000 total rows
    const int Etot = nA + nB + nM + nM;         // 5.5M edges

    float* out      = (float*)d_out;
    float* user_out = out + (size_t)n_entities * DD;

    // workspace (~105 MB)
    float* ws = (float*)d_ws;
    size_t off = 0;
    float* kg_item = ws + off; off += (size_t)n_items * DD;
    float* ukg     = ws + off; off += (size_t)n_users * DD;
    float* iu      = ws + off; off += (size_t)n_items * DD;
    float* ui      = ws + off; off += (size_t)n_users * DD;
    int* ibase  = (int*)(ws + off);
    int* counts = ibase;            // R
    int* rowptr = ibase + R;        // R
    int* bsums  = ibase + 2 * R;    // 512
    int* pay    = ibase + 2 * R + 512;  // Etot

    hipMemsetAsync(counts, 0, (size_t)R * sizeof(int), stream);

    unsigned gE = (Etot + 255) / 256;
    hist_all<<<gE, 256, 0, stream>>>(edge_index, uedge_index, mat_col, mat_row,
                                     nA, nB, nM, nM, offA, offB, offC, offD, counts);
    int nb = (R + 1023) / 1024;   // 469 <= 512
    scan_blocks<<<nb, 256, 0, stream>>>(counts, rowptr, bsums, R);
    scan_sums<<<1, 512, 0, stream>>>(bsums, nb);
    add_offsets<<<(R + 255) / 256, 256, 0, stream>>>(rowptr, bsums, R);
    fill_all<<<gE, 256, 0, stream>>>(edge_index, edge_index + nA, edge_type,
                                     uedge_index, uedge_index + nB, uedge_type,
                                     mat_col, mat_row,
                                     mat_row, mat_col,
                                     nA, nB, nM, nM, offA, offB, offC, offD,
                                     rowptr, pay);
    gather_all<<<(R + 3) / 4, 256, 0, stream>>>(entity_emb, user_emb, weight,
                                                rowptr, pay,
                                                kg_item, out, ukg, user_out, iu, ui,
                                                offB, offC, offD, R, n_items, n_users);

    // items: gi = sig(kg@g1.T + iu@g2.T); out = gi*kg + (1-gi)*iu
    gate_fuse_kernel<<<1024, 256, 0, stream>>>(kg_item, iu, g1, g2, out, n_items);
    // users: hi = sig(ui@g2.T + ukg@g3.T); out = hi*ukg + (1-hi)*ui
    gate_fuse_kernel<<<2048, 256, 0, stream>>>(ukg, ui, g3, g2, user_out, n_users);
}